// Round 1
// baseline (373.563 us; speedup 1.0000x reference)
//
#include <hip/hip_runtime.h>

using bf16x8 = __attribute__((ext_vector_type(8))) __bf16;
using f32x4  = __attribute__((ext_vector_type(4))) float;
using u16 = unsigned short;

constexpr int Bb = 16, Nn = 512, Ee = 768, Hh = 12, Dd = 64;

__device__ inline u16 f2b(float x) {
  union { float f; unsigned int u; } v; v.f = x;
  unsigned int r = v.u + 0x7fffu + ((v.u >> 16) & 1u);
  return (u16)(r >> 16);
}

// ---------- K0: convert the 4 weight matrices f32 -> bf16 ----------
__global__ void k_cvtw(const float* __restrict__ w0, const float* __restrict__ w1,
                       const float* __restrict__ w2, const float* __restrict__ w3,
                       u16* __restrict__ dst) {
  int idx = blockIdx.x * 256 + threadIdx.x;     // one float4 per thread
  constexpr int per = Ee * Ee / 4;              // 147456
  int m = idx / per, r = idx - m * per;
  const float* src = (m == 0) ? w0 : (m == 1) ? w1 : (m == 2) ? w2 : w3;
  float4 v = reinterpret_cast<const float4*>(src)[r];
  ushort4 o = make_ushort4(f2b(v.x), f2b(v.y), f2b(v.z), f2b(v.w));
  reinterpret_cast<ushort4*>(dst)[idx] = o;
}

// ---------- K0b: combined bias = spatial + edge (f32) ----------
__global__ void k_biascomb(const float* __restrict__ sb, const float* __restrict__ eb,
                           float* __restrict__ cb) {
  int i = blockIdx.x * 256 + threadIdx.x;
  float4 a = reinterpret_cast<const float4*>(sb)[i];
  float4 b = reinterpret_cast<const float4*>(eb)[i];
  reinterpret_cast<float4*>(cb)[i] = make_float4(a.x + b.x, a.y + b.y, a.z + b.z, a.w + b.w);
}

// ---------- K1: QKV projection GEMM (128x128x32 tile, 4 waves) ----------
__global__ __launch_bounds__(256, 2)
void k_qkv(const float* __restrict__ xq, const float* __restrict__ xk, const float* __restrict__ xv,
           const u16* __restrict__ wb, const float* __restrict__ bq, const float* __restrict__ bk,
           const float* __restrict__ bv, u16* __restrict__ Q, u16* __restrict__ K,
           u16* __restrict__ VT) {
  const int mat = blockIdx.z;
  const float* X = (mat == 0) ? xq : (mat == 1) ? xk : xv;
  const u16* W = wb + (size_t)mat * Ee * Ee;
  const float* bias = (mat == 0) ? bq : (mat == 1) ? bk : bv;
  const int bm = blockIdx.x, bn = blockIdx.y;
  const int tid = threadIdx.x, lane = tid & 63, wid = tid >> 6;
  const int wr = wid >> 1, wc = wid & 1;

  __shared__ u16 As[2][128 * 40];   // pad 32->40 bf16 per row (80B, 16B-multiple)
  __shared__ u16 Bs[2][128 * 40];

  f32x4 acc[4][4] = {};
  float4 ar[4];
  int4 br[2];

  auto loadA = [&](int it) {
    const int c4 = (tid & 7) * 4, r = tid >> 3;
    const float* p = X + (size_t)(bm * 128 + r) * Ee + it * 32 + c4;
#pragma unroll
    for (int i = 0; i < 4; ++i)
      ar[i] = *reinterpret_cast<const float4*>(p + (size_t)(i * 32) * Ee);
  };
  auto loadB = [&](int it) {
    const int c8 = (tid & 3) * 8, r = tid >> 2;
    const u16* p = W + (size_t)(bn * 128 + r) * Ee + it * 32 + c8;
#pragma unroll
    for (int i = 0; i < 2; ++i)
      br[i] = *reinterpret_cast<const int4*>(p + (size_t)(i * 64) * Ee);
  };
  auto writeLds = [&](int buf) {
    const int rA = tid >> 3, cA = (tid & 7) * 4;
#pragma unroll
    for (int i = 0; i < 4; ++i) {
      float4 v = ar[i];
      ushort4 u = make_ushort4(f2b(v.x), f2b(v.y), f2b(v.z), f2b(v.w));
      *reinterpret_cast<ushort4*>(&As[buf][(rA + i * 32) * 40 + cA]) = u;
    }
    const int rB = tid >> 2, cB = (tid & 3) * 8;
#pragma unroll
    for (int i = 0; i < 2; ++i)
      *reinterpret_cast<int4*>(&Bs[buf][(rB + i * 64) * 40 + cB]) = br[i];
  };
  auto compute = [&](int buf) {
    bf16x8 a[4], b[4];
#pragma unroll
    for (int mt = 0; mt < 4; ++mt)
      a[mt] = *reinterpret_cast<const bf16x8*>(
          &As[buf][(wr * 64 + mt * 16 + (lane & 15)) * 40 + (lane >> 4) * 8]);
#pragma unroll
    for (int nt = 0; nt < 4; ++nt)
      b[nt] = *reinterpret_cast<const bf16x8*>(
          &Bs[buf][(wc * 64 + nt * 16 + (lane & 15)) * 40 + (lane >> 4) * 8]);
#pragma unroll
    for (int mt = 0; mt < 4; ++mt)
#pragma unroll
      for (int nt = 0; nt < 4; ++nt)
        acc[mt][nt] = __builtin_amdgcn_mfma_f32_16x16x32_bf16(a[mt], b[nt], acc[mt][nt], 0, 0, 0);
  };

  loadA(0); loadB(0); writeLds(0);
  __syncthreads();
  int buf = 0;
  for (int it = 0; it < 24; ++it) {
    if (it + 1 < 24) { loadA(it + 1); loadB(it + 1); }
    compute(buf);
    if (it + 1 < 24) writeLds(buf ^ 1);
    __syncthreads();
    buf ^= 1;
  }

#pragma unroll
  for (int mt = 0; mt < 4; ++mt) {
#pragma unroll
    for (int nt = 0; nt < 4; ++nt) {
      const int ecol = bn * 128 + wc * 64 + nt * 16 + (lane & 15);
      const int r0 = bm * 128 + wr * 64 + mt * 16 + ((lane >> 4) << 2);
      const int bb = r0 >> 9, n0 = r0 & 511;
      const int h = ecol >> 6, d = ecol & 63;
      const float bs = bias[ecol];
      f32x4 v = acc[mt][nt];
      if (mat == 2) {
        ushort4 u = make_ushort4(f2b(v[0] + bs), f2b(v[1] + bs), f2b(v[2] + bs), f2b(v[3] + bs));
        *reinterpret_cast<ushort4*>(&VT[((size_t)(bb * Hh + h) * Dd + d) * Nn + n0]) = u;
      } else {
        u16* dst = (mat == 0) ? Q : K;
        const float sc = (mat == 0) ? 0.125f : 1.0f;  // fold d^-0.5 into Q
#pragma unroll
        for (int j = 0; j < 4; ++j)
          dst[((size_t)(bb * Hh + h) * Nn + (n0 + j)) * Dd + d] = f2b((v[j] + bs) * sc);
      }
    }
  }
}

// ---------- K2: scores = QK^T + bias, softmax, write f32 weights ----------
__global__ __launch_bounds__(256, 2)
void k_scores(const u16* __restrict__ Q, const u16* __restrict__ K,
              const float* __restrict__ cb, float* __restrict__ wout) {
  const int qb = blockIdx.x, h = blockIdx.y, b = blockIdx.z;
  const int bh = b * Hh + h;
  const int q0 = qb * 64;
  const int tid = threadIdx.x, lane = tid & 63, wid = tid >> 6;

  __shared__ u16 Ksm[2][64 * 64];   // [key][d] bf16, XOR-swizzled 16B chunks

  bf16x8 aq[2];
  {
    const u16* qp = Q + ((size_t)bh * Nn + q0 + wid * 16 + (lane & 15)) * Dd + (lane >> 4) * 8;
    aq[0] = *reinterpret_cast<const bf16x8*>(qp);
    aq[1] = *reinterpret_cast<const bf16x8*>(qp + 32);
  }

  f32x4 acc[32] = {};
  int4 kreg[2];

  auto loadK = [&](int kt) {
#pragma unroll
    for (int i = 0; i < 2; ++i) {
      const int s = i * 256 + tid, row = s >> 3, c8 = s & 7;
      kreg[i] = *reinterpret_cast<const int4*>(
          K + ((size_t)bh * Nn + kt * 64 + row) * Dd + c8 * 8);
    }
  };
  auto writeK = [&](int buf) {
#pragma unroll
    for (int i = 0; i < 2; ++i) {
      const int s = i * 256 + tid, row = s >> 3, c8 = s & 7;
      *reinterpret_cast<int4*>(reinterpret_cast<char*>(Ksm[buf]) + row * 128 +
                               ((c8 ^ (row & 7)) * 16)) = kreg[i];
    }
  };

  loadK(0); writeK(0);
  __syncthreads();
  int buf = 0;
#pragma unroll
  for (int kt = 0; kt < 8; ++kt) {
    if (kt + 1 < 8) loadK(kt + 1);
#pragma unroll
    for (int kk = 0; kk < 2; ++kk) {
#pragma unroll
      for (int ct = 0; ct < 4; ++ct) {
        const int kr = ct * 16 + (lane & 15);
        const int chunk = (lane >> 4) + kk * 4;
        bf16x8 bk = *reinterpret_cast<const bf16x8*>(
            reinterpret_cast<const char*>(Ksm[buf]) + kr * 128 + ((chunk ^ (kr & 7)) * 16));
        acc[kt * 4 + ct] = __builtin_amdgcn_mfma_f32_16x16x32_bf16(aq[kk], bk, acc[kt * 4 + ct], 0, 0, 0);
      }
    }
    if (kt + 1 < 8) writeK(buf ^ 1);
    __syncthreads();
    buf ^= 1;
  }

  // epilogue: +bias, softmax over the full 512-wide row, write f32 weights
  const int c = lane & 15;
  const int rq = q0 + wid * 16 + ((lane >> 4) << 2);
  const float* cbp = cb + ((size_t)b * Nn + rq) * Nn + c;
#pragma unroll
  for (int j = 0; j < 4; ++j)
#pragma unroll
    for (int t = 0; t < 32; ++t)
      acc[t][j] += cbp[(size_t)j * Nn + t * 16];

  float mx[4] = {-1e30f, -1e30f, -1e30f, -1e30f};
#pragma unroll
  for (int t = 0; t < 32; ++t)
#pragma unroll
    for (int j = 0; j < 4; ++j) mx[j] = fmaxf(mx[j], acc[t][j]);
#pragma unroll
  for (int off = 1; off < 16; off <<= 1)
#pragma unroll
    for (int j = 0; j < 4; ++j) mx[j] = fmaxf(mx[j], __shfl_xor(mx[j], off, 16));

  float sum[4] = {0.f, 0.f, 0.f, 0.f};
#pragma unroll
  for (int t = 0; t < 32; ++t)
#pragma unroll
    for (int j = 0; j < 4; ++j) {
      float p = exp2f((acc[t][j] - mx[j]) * 1.44269504f);
      acc[t][j] = p;
      sum[j] += p;
    }
#pragma unroll
  for (int off = 1; off < 16; off <<= 1)
#pragma unroll
    for (int j = 0; j < 4; ++j) sum[j] += __shfl_xor(sum[j], off, 16);

  float* wp = wout + ((size_t)bh * Nn + rq) * Nn + c;
#pragma unroll
  for (int j = 0; j < 4; ++j) {
    const float inv = 1.0f / sum[j];
#pragma unroll
    for (int t = 0; t < 32; ++t)
      wp[(size_t)j * Nn + t * 16] = acc[t][j] * inv;
  }
}

// ---------- K3: PV GEMM: O = W[512x512] @ V[512x64] ----------
__global__ __launch_bounds__(256, 2)
void k_pv(const float* __restrict__ wts, const u16* __restrict__ VT, u16* __restrict__ AO) {
  const int qb = blockIdx.x, h = blockIdx.y, b = blockIdx.z;
  const int bh = b * Hh + h;
  const int q0 = qb * 64;
  const int tid = threadIdx.x, lane = tid & 63, wid = tid >> 6;

  __shared__ u16 Ps[2][64 * 64];   // [q][key] bf16, XOR-swizzled

  f32x4 acc[4] = {};
  float4 pr[4];

  auto loadP = [&](int kt) {
    const int row = tid >> 4, c4 = (tid & 15) * 4;
    const float* p = wts + ((size_t)bh * Nn + q0 + row) * Nn + kt * 64 + c4;
#pragma unroll
    for (int i = 0; i < 4; ++i)
      pr[i] = *reinterpret_cast<const float4*>(p + (size_t)(i * 16) * Nn);
  };
  auto writeP = [&](int buf) {
    const int row0 = tid >> 4, c4 = (tid & 15) * 4;
#pragma unroll
    for (int i = 0; i < 4; ++i) {
      const int row = row0 + i * 16;
      float4 v = pr[i];
      ushort4 u = make_ushort4(f2b(v.x), f2b(v.y), f2b(v.z), f2b(v.w));
      *reinterpret_cast<ushort4*>(reinterpret_cast<char*>(Ps[buf]) + row * 128 +
                                  ((c4 * 2) ^ ((row & 7) << 4))) = u;
    }
  };

  loadP(0); writeP(0);
  __syncthreads();
  int buf = 0;
  for (int kt = 0; kt < 8; ++kt) {
    if (kt + 1 < 8) loadP(kt + 1);
#pragma unroll
    for (int kk = 0; kk < 2; ++kk) {
      const int qr = wid * 16 + (lane & 15);
      const int chunk = (lane >> 4) + kk * 4;
      bf16x8 pa = *reinterpret_cast<const bf16x8*>(
          reinterpret_cast<const char*>(Ps[buf]) + qr * 128 + ((chunk ^ (qr & 7)) * 16));
#pragma unroll
      for (int ct = 0; ct < 4; ++ct) {
        const u16* vp = VT + ((size_t)bh * Dd + ct * 16 + (lane & 15)) * Nn +
                        kt * 64 + kk * 32 + (lane >> 4) * 8;
        bf16x8 bv2 = *reinterpret_cast<const bf16x8*>(vp);
        acc[ct] = __builtin_amdgcn_mfma_f32_16x16x32_bf16(pa, bv2, acc[ct], 0, 0, 0);
      }
    }
    if (kt + 1 < 8) writeP(buf ^ 1);
    __syncthreads();
    buf ^= 1;
  }

  const int n0 = q0 + wid * 16 + ((lane >> 4) << 2);
#pragma unroll
  for (int ct = 0; ct < 4; ++ct) {
    const int d = ct * 16 + (lane & 15);
#pragma unroll
    for (int j = 0; j < 4; ++j)
      AO[((size_t)b * Nn + n0 + j) * Ee + h * Dd + d] = f2b(acc[ct][j]);
  }
}

// ---------- K4: output projection GEMM -> f32 out ----------
__global__ __launch_bounds__(256, 2)
void k_outproj(const u16* __restrict__ AOp, const u16* __restrict__ Wo,
               const float* __restrict__ bo, float* __restrict__ out) {
  const int bm = blockIdx.x, bn = blockIdx.y;
  const int tid = threadIdx.x, lane = tid & 63, wid = tid >> 6;
  const int wr = wid >> 1, wc = wid & 1;

  __shared__ u16 As[2][128 * 40];
  __shared__ u16 Bs[2][128 * 40];

  f32x4 acc[4][4] = {};
  int4 ar2[2], br2[2];

  auto loadA = [&](int it) {
    const int c8 = (tid & 3) * 8, r = tid >> 2;
    const u16* p = AOp + (size_t)(bm * 128 + r) * Ee + it * 32 + c8;
#pragma unroll
    for (int i = 0; i < 2; ++i)
      ar2[i] = *reinterpret_cast<const int4*>(p + (size_t)(i * 64) * Ee);
  };
  auto loadB = [&](int it) {
    const int c8 = (tid & 3) * 8, r = tid >> 2;
    const u16* p = Wo + (size_t)(bn * 128 + r) * Ee + it * 32 + c8;
#pragma unroll
    for (int i = 0; i < 2; ++i)
      br2[i] = *reinterpret_cast<const int4*>(p + (size_t)(i * 64) * Ee);
  };
  auto writeLds = [&](int buf) {
    const int rB = tid >> 2, cB = (tid & 3) * 8;
#pragma unroll
    for (int i = 0; i < 2; ++i) {
      *reinterpret_cast<int4*>(&As[buf][(rB + i * 64) * 40 + cB]) = ar2[i];
      *reinterpret_cast<int4*>(&Bs[buf][(rB + i * 64) * 40 + cB]) = br2[i];
    }
  };
  auto compute = [&](int buf) {
    bf16x8 a[4], b[4];
#pragma unroll
    for (int mt = 0; mt < 4; ++mt)
      a[mt] = *reinterpret_cast<const bf16x8*>(
          &As[buf][(wr * 64 + mt * 16 + (lane & 15)) * 40 + (lane >> 4) * 8]);
#pragma unroll
    for (int nt = 0; nt < 4; ++nt)
      b[nt] = *reinterpret_cast<const bf16x8*>(
          &Bs[buf][(wc * 64 + nt * 16 + (lane & 15)) * 40 + (lane >> 4) * 8]);
#pragma unroll
    for (int mt = 0; mt < 4; ++mt)
#pragma unroll
      for (int nt = 0; nt < 4; ++nt)
        acc[mt][nt] = __builtin_amdgcn_mfma_f32_16x16x32_bf16(a[mt], b[nt], acc[mt][nt], 0, 0, 0);
  };

  loadA(0); loadB(0); writeLds(0);
  __syncthreads();
  int buf = 0;
  for (int it = 0; it < 24; ++it) {
    if (it + 1 < 24) { loadA(it + 1); loadB(it + 1); }
    compute(buf);
    if (it + 1 < 24) writeLds(buf ^ 1);
    __syncthreads();
    buf ^= 1;
  }

#pragma unroll
  for (int mt = 0; mt < 4; ++mt) {
#pragma unroll
    for (int nt = 0; nt < 4; ++nt) {
      const int ecol = bn * 128 + wc * 64 + nt * 16 + (lane & 15);
      const int r0 = bm * 128 + wr * 64 + mt * 16 + ((lane >> 4) << 2);
      const float bs = bo[ecol];
      f32x4 v = acc[mt][nt];
#pragma unroll
      for (int j = 0; j < 4; ++j)
        out[(size_t)(r0 + j) * Ee + ecol] = v[j] + bs;
    }
  }
}

// ---------- launch ----------
extern "C" void kernel_launch(void* const* d_in, const int* in_sizes, int n_in,
                              void* d_out, int out_size, void* d_ws, size_t ws_size,
                              hipStream_t stream) {
  const float* query  = (const float*)d_in[0];
  const float* key_in = (const float*)d_in[1];
  const float* value  = (const float*)d_in[2];
  const float* sb     = (const float*)d_in[3];
  const float* eb     = (const float*)d_in[4];
  const float* Wq     = (const float*)d_in[5];
  const float* bq     = (const float*)d_in[6];
  const float* Wk     = (const float*)d_in[7];
  const float* bk     = (const float*)d_in[8];
  const float* Wv     = (const float*)d_in[9];
  const float* bv     = (const float*)d_in[10];
  const float* Wo     = (const float*)d_in[11];
  const float* bo     = (const float*)d_in[12];

  float* out0 = (float*)d_out;                        // attn_output [16,512,768]
  float* wout = out0 + (size_t)Bb * Nn * Ee;          // attn_weights [16,12,512,512]

  // workspace layout (bytes)
  char* ws = (char*)d_ws;
  const size_t off_wb = 0;                 // 4 * 768*768 bf16 = 4,718,592
  const size_t off_cb = 4718592;           // combined bias f32 = 16,777,216
  const size_t off_Q  = 21495808;          // 12,582,912 each
  const size_t off_K  = 34078720;
  const size_t off_VT = 46661632;
  const size_t off_AO = 59244544;          // end 71,827,456
  if (ws_size < 71827456) return;          // fail loudly (poisoned output) rather than corrupt

  u16*  wb  = (u16*)(ws + off_wb);
  float* cbf = (float*)(ws + off_cb);
  u16*  Qs  = (u16*)(ws + off_Q);
  u16*  Kst = (u16*)(ws + off_K);
  u16*  VTs = (u16*)(ws + off_VT);
  u16*  AO  = (u16*)(ws + off_AO);

  k_cvtw<<<2304, 256, 0, stream>>>(Wq, Wk, Wv, Wo, wb);
  k_biascomb<<<4096, 256, 0, stream>>>(sb, eb, cbf);
  k_qkv<<<dim3(64, 6, 3), 256, 0, stream>>>(query, key_in, value, wb, bq, bk, bv, Qs, Kst, VTs);
  k_scores<<<dim3(8, Hh, Bb), 256, 0, stream>>>(Qs, Kst, cbf, wout);
  k_pv<<<dim3(8, Hh, Bb), 256, 0, stream>>>(wout, VTs, AO);
  k_outproj<<<dim3(64, 6), 256, 0, stream>>>(AO, wb + 3 * Ee * Ee, bo, out0);
}

// Round 3
// 291.871 us; speedup vs baseline: 1.2799x; 1.2799x over previous
//
#include <hip/hip_runtime.h>

using bf16x8 = __attribute__((ext_vector_type(8))) __bf16;
using f32x4  = __attribute__((ext_vector_type(4))) float;
using u16 = unsigned short;

constexpr int Bb = 16, Nn = 512, Ee = 768, Hh = 12, Dd = 64;

__device__ inline u16 f2b(float x) {
  union { float f; unsigned int u; } v; v.f = x;
  unsigned int r = v.u + 0x7fffu + ((v.u >> 16) & 1u);
  return (u16)(r >> 16);
}

__device__ inline unsigned cvtpk(float lo, float hi) {
  unsigned r;
  asm("v_cvt_pk_bf16_f32 %0, %1, %2" : "=v"(r) : "v"(lo), "v"(hi));
  return r;
}

__device__ inline void gload16(const void* g, void* l) {
  __builtin_amdgcn_global_load_lds((const __attribute__((address_space(1))) void*)g,
                                   (__attribute__((address_space(3))) void*)l, 16, 0, 0);
}

// ---------- K0: convert the 4 weight matrices f32 -> bf16 ----------
__global__ void k_cvtw(const float* __restrict__ w0, const float* __restrict__ w1,
                       const float* __restrict__ w2, const float* __restrict__ w3,
                       u16* __restrict__ dst) {
  int idx = blockIdx.x * 256 + threadIdx.x;     // one float4 per thread
  constexpr int per = Ee * Ee / 4;              // 147456
  int m = idx / per, r = idx - m * per;
  const float* src = (m == 0) ? w0 : (m == 1) ? w1 : (m == 2) ? w2 : w3;
  float4 v = reinterpret_cast<const float4*>(src)[r];
  ushort4 o = make_ushort4(f2b(v.x), f2b(v.y), f2b(v.z), f2b(v.w));
  reinterpret_cast<ushort4*>(dst)[idx] = o;
}

// ---------- K1: QKV projection GEMM, m97-style global_load_lds staging ----------
// A tile staged as f32 [128][32] (8 slots of 16B/row, xor-swizzled source),
// B tile bf16 [128][32] (4 slots, xor-swizzled). LDS dest linear (m104).
__global__ __launch_bounds__(256, 3)
void k_qkv(const float* __restrict__ xq, const float* __restrict__ xk, const float* __restrict__ xv,
           const u16* __restrict__ wb, const float* __restrict__ bq, const float* __restrict__ bk,
           const float* __restrict__ bv, u16* __restrict__ Q, u16* __restrict__ K,
           u16* __restrict__ VT) {
  const int mat = blockIdx.z;
  const float* X = (mat == 0) ? xq : (mat == 1) ? xk : xv;
  const u16* W = wb + (size_t)mat * Ee * Ee;
  const float* bias = (mat == 0) ? bq : (mat == 1) ? bk : bv;
  const int bm = blockIdx.x, bn = blockIdx.y;
  const int tid = threadIdx.x, lane = tid & 63, wid = tid >> 6;
  const int wr = wid >> 1, wc = wid & 1;

  __shared__ char smem[49152];   // A: 2x16KB at 0; B: 2x8KB at 32768

  auto stageA = [&](int buf, int it) {
    const int r0 = tid >> 3, s = tid & 7;
    char* lbase = smem + buf * 16384 + tid * 16;
#pragma unroll
    for (int R = 0; R < 4; ++R) {
      const int row = R * 32 + r0;
      const int ch = s ^ (row & 7);
      gload16(X + (size_t)(bm * 128 + row) * Ee + it * 32 + ch * 4, lbase + R * 4096);
    }
  };
  auto stageB = [&](int buf, int it) {
    const int r0 = tid >> 2, s = tid & 3;
    char* lbase = smem + 32768 + buf * 8192 + tid * 16;
#pragma unroll
    for (int R = 0; R < 2; ++R) {
      const int row = R * 64 + r0;
      const int ch = s ^ ((row >> 1) & 3);
      gload16(W + (size_t)(bn * 128 + row) * Ee + it * 32 + ch * 8, lbase + R * 4096);
    }
  };

  f32x4 acc[4][4] = {};

  auto compute = [&](int buf) {
    const char* Ab = smem + buf * 16384;
    const char* Bbp = smem + 32768 + buf * 8192;
    const int q = lane >> 4;
    bf16x8 a[4], b[4];
#pragma unroll
    for (int mt = 0; mt < 4; ++mt) {
      const int row = wr * 64 + mt * 16 + (lane & 15);
      const int s0 = (2 * q) ^ (row & 7), s1 = (2 * q + 1) ^ (row & 7);
      f32x4 f0 = *reinterpret_cast<const f32x4*>(Ab + row * 128 + s0 * 16);
      f32x4 f1 = *reinterpret_cast<const f32x4*>(Ab + row * 128 + s1 * 16);
      union { unsigned u[4]; bf16x8 v; } cv;
      cv.u[0] = cvtpk(f0[0], f0[1]);
      cv.u[1] = cvtpk(f0[2], f0[3]);
      cv.u[2] = cvtpk(f1[0], f1[1]);
      cv.u[3] = cvtpk(f1[2], f1[3]);
      a[mt] = cv.v;
    }
#pragma unroll
    for (int nt = 0; nt < 4; ++nt) {
      const int row = wc * 64 + nt * 16 + (lane & 15);
      const int s = q ^ ((row >> 1) & 3);
      b[nt] = *reinterpret_cast<const bf16x8*>(Bbp + row * 64 + s * 16);
    }
#pragma unroll
    for (int mt = 0; mt < 4; ++mt)
#pragma unroll
      for (int nt = 0; nt < 4; ++nt)
        acc[mt][nt] = __builtin_amdgcn_mfma_f32_16x16x32_bf16(a[mt], b[nt], acc[mt][nt], 0, 0, 0);
  };

  stageA(0, 0); stageB(0, 0);
  __syncthreads();
  int buf = 0;
  for (int it = 0; it < 24; ++it) {
    if (it + 1 < 24) { stageA(buf ^ 1, it + 1); stageB(buf ^ 1, it + 1); }
    compute(buf);
    __syncthreads();
    buf ^= 1;
  }

  // epilogue via LDS transpose tile [128][136] u16 for coalesced 128B stores
  u16* sm16 = (u16*)smem;
  if (mat < 2) {
    u16* dst = (mat == 0) ? Q : K;
    const float sc = (mat == 0) ? 0.125f : 1.0f;
#pragma unroll
    for (int mt = 0; mt < 4; ++mt) {
      const int n_l0 = wr * 64 + mt * 16 + ((lane >> 4) << 2);
#pragma unroll
      for (int nt = 0; nt < 4; ++nt) {
        const int e_l = wc * 64 + nt * 16 + (lane & 15);
        const float bs = bias[bn * 128 + e_l];
#pragma unroll
        for (int j = 0; j < 4; ++j)
          sm16[(n_l0 + j) * 136 + e_l] = f2b((acc[mt][nt][j] + bs) * sc);
      }
    }
    __syncthreads();
    const int row = tid >> 1, half = tid & 1;
    const int n = bm * 128 + row, b = n >> 9, n0 = n & 511, h = bn * 2 + half;
    u16* gp = dst + ((size_t)(b * Hh + h) * Nn + n0) * Dd;
    const u16* sp = sm16 + row * 136 + half * 64;
#pragma unroll
    for (int i = 0; i < 8; ++i)                      // 8 x int4 = 64 u16 = full d-range
      *reinterpret_cast<int4*>(gp + i * 8) = *reinterpret_cast<const int4*>(sp + i * 8);
  } else {
#pragma unroll
    for (int mt = 0; mt < 4; ++mt) {
      const int n_l0 = wr * 64 + mt * 16 + ((lane >> 4) << 2);
#pragma unroll
      for (int nt = 0; nt < 4; ++nt) {
        const int e_l = wc * 64 + nt * 16 + (lane & 15);
        const float bs = bias[bn * 128 + e_l];
#pragma unroll
        for (int j = 0; j < 4; ++j)
          sm16[e_l * 136 + n_l0 + j] = f2b(acc[mt][nt][j] + bs);
      }
    }
    __syncthreads();
    const int er = tid >> 1, half = tid & 1;
    const int b = bm >> 2, h = bn * 2 + (er >> 6), d = er & 63;
    u16* gp = VT + ((size_t)(b * Hh + h) * Dd + d) * Nn + (bm & 3) * 128 + half * 64;
    const u16* sp = sm16 + er * 136 + half * 64;
#pragma unroll
    for (int i = 0; i < 8; ++i)                      // 8 x int4 = 64 u16 = full token-half
      *reinterpret_cast<int4*>(gp + i * 8) = *reinterpret_cast<const int4*>(sp + i * 8);
  }
}

// ---------- K2: scores = QK^T + (spatial+edge), softmax, write f32 weights ----------
__global__ __launch_bounds__(256, 2)
void k_scores(const u16* __restrict__ Q, const u16* __restrict__ K,
              const float* __restrict__ sb, const float* __restrict__ eb,
              float* __restrict__ wout) {
  const int qb = blockIdx.x, h = blockIdx.y, b = blockIdx.z;
  const int bh = b * Hh + h;
  const int q0 = qb * 64;
  const int tid = threadIdx.x, lane = tid & 63, wid = tid >> 6;

  __shared__ u16 Ksm[2][64 * 64];   // [key][d] bf16, XOR-swizzled 16B chunks

  bf16x8 aq[2];
  {
    const u16* qp = Q + ((size_t)bh * Nn + q0 + wid * 16 + (lane & 15)) * Dd + (lane >> 4) * 8;
    aq[0] = *reinterpret_cast<const bf16x8*>(qp);
    aq[1] = *reinterpret_cast<const bf16x8*>(qp + 32);
  }

  f32x4 acc[32] = {};
  int4 kreg[2];

  auto loadK = [&](int kt) {
#pragma unroll
    for (int i = 0; i < 2; ++i) {
      const int s = i * 256 + tid, row = s >> 3, c8 = s & 7;
      kreg[i] = *reinterpret_cast<const int4*>(
          K + ((size_t)bh * Nn + kt * 64 + row) * Dd + c8 * 8);
    }
  };
  auto writeK = [&](int buf) {
#pragma unroll
    for (int i = 0; i < 2; ++i) {
      const int s = i * 256 + tid, row = s >> 3, c8 = s & 7;
      *reinterpret_cast<int4*>(reinterpret_cast<char*>(Ksm[buf]) + row * 128 +
                               ((c8 ^ (row & 7)) * 16)) = kreg[i];
    }
  };

  loadK(0); writeK(0);
  __syncthreads();
  int buf = 0;
#pragma unroll
  for (int kt = 0; kt < 8; ++kt) {
    if (kt + 1 < 8) loadK(kt + 1);
#pragma unroll
    for (int kk = 0; kk < 2; ++kk) {
#pragma unroll
      for (int ct = 0; ct < 4; ++ct) {
        const int kr = ct * 16 + (lane & 15);
        const int chunk = (lane >> 4) + kk * 4;
        bf16x8 bk = *reinterpret_cast<const bf16x8*>(
            reinterpret_cast<const char*>(Ksm[buf]) + kr * 128 + ((chunk ^ (kr & 7)) * 16));
        acc[kt * 4 + ct] = __builtin_amdgcn_mfma_f32_16x16x32_bf16(aq[kk], bk, acc[kt * 4 + ct], 0, 0, 0);
      }
    }
    if (kt + 1 < 8) writeK(buf ^ 1);
    __syncthreads();
    buf ^= 1;
  }

  // epilogue: +bias (spatial+edge), softmax over 512-wide row, write f32 weights
  const int c = lane & 15;
  const int rq = q0 + wid * 16 + ((lane >> 4) << 2);
  const float* sbp = sb + ((size_t)b * Nn + rq) * Nn + c;
  const float* ebp = eb + ((size_t)b * Nn + rq) * Nn + c;
#pragma unroll
  for (int j = 0; j < 4; ++j)
#pragma unroll
    for (int t = 0; t < 32; ++t)
      acc[t][j] += sbp[(size_t)j * Nn + t * 16] + ebp[(size_t)j * Nn + t * 16];

  float mx[4] = {-1e30f, -1e30f, -1e30f, -1e30f};
#pragma unroll
  for (int t = 0; t < 32; ++t)
#pragma unroll
    for (int j = 0; j < 4; ++j) mx[j] = fmaxf(mx[j], acc[t][j]);
#pragma unroll
  for (int off = 1; off < 16; off <<= 1)
#pragma unroll
    for (int j = 0; j < 4; ++j) mx[j] = fmaxf(mx[j], __shfl_xor(mx[j], off, 16));

  float sum[4] = {0.f, 0.f, 0.f, 0.f};
#pragma unroll
  for (int t = 0; t < 32; ++t)
#pragma unroll
    for (int j = 0; j < 4; ++j) {
      float p = exp2f((acc[t][j] - mx[j]) * 1.44269504f);
      acc[t][j] = p;
      sum[j] += p;
    }
#pragma unroll
  for (int off = 1; off < 16; off <<= 1)
#pragma unroll
    for (int j = 0; j < 4; ++j) sum[j] += __shfl_xor(sum[j], off, 16);

  float* wp = wout + ((size_t)bh * Nn + rq) * Nn + c;
#pragma unroll
  for (int j = 0; j < 4; ++j) {
    const float inv = 1.0f / sum[j];
#pragma unroll
    for (int t = 0; t < 32; ++t)
      wp[(size_t)j * Nn + t * 16] = acc[t][j] * inv;
  }
}

// ---------- K3: PV GEMM: O = W[512x512] @ V[512x64] ----------
__global__ __launch_bounds__(256, 2)
void k_pv(const float* __restrict__ wts, const u16* __restrict__ VT, u16* __restrict__ AO) {
  const int qb = blockIdx.x, h = blockIdx.y, b = blockIdx.z;
  const int bh = b * Hh + h;
  const int q0 = qb * 64;
  const int tid = threadIdx.x, lane = tid & 63, wid = tid >> 6;

  __shared__ u16 Ps[2][64 * 64];   // [q][key] bf16, XOR-swizzled

  f32x4 acc[4] = {};
  float4 pr[4];

  auto loadP = [&](int kt) {
    const int row = tid >> 4, c4 = (tid & 15) * 4;
    const float* p = wts + ((size_t)bh * Nn + q0 + row) * Nn + kt * 64 + c4;
#pragma unroll
    for (int i = 0; i < 4; ++i)
      pr[i] = *reinterpret_cast<const float4*>(p + (size_t)(i * 16) * Nn);
  };
  auto writeP = [&](int buf) {
    const int row0 = tid >> 4, c4 = (tid & 15) * 4;
#pragma unroll
    for (int i = 0; i < 4; ++i) {
      const int row = row0 + i * 16;
      float4 v = pr[i];
      ushort4 u = make_ushort4(f2b(v.x), f2b(v.y), f2b(v.z), f2b(v.w));
      *reinterpret_cast<ushort4*>(reinterpret_cast<char*>(Ps[buf]) + row * 128 +
                                  ((c4 * 2) ^ ((row & 7) << 4))) = u;
    }
  };

  loadP(0); writeP(0);
  __syncthreads();
  int buf = 0;
  for (int kt = 0; kt < 8; ++kt) {
    if (kt + 1 < 8) loadP(kt + 1);
#pragma unroll
    for (int kk = 0; kk < 2; ++kk) {
      const int qr = wid * 16 + (lane & 15);
      const int chunk = (lane >> 4) + kk * 4;
      bf16x8 pa = *reinterpret_cast<const bf16x8*>(
          reinterpret_cast<const char*>(Ps[buf]) + qr * 128 + ((chunk ^ (qr & 7)) * 16));
#pragma unroll
      for (int ct = 0; ct < 4; ++ct) {
        const u16* vp = VT + ((size_t)bh * Dd + ct * 16 + (lane & 15)) * Nn +
                        kt * 64 + kk * 32 + (lane >> 4) * 8;
        bf16x8 bv2 = *reinterpret_cast<const bf16x8*>(vp);
        acc[ct] = __builtin_amdgcn_mfma_f32_16x16x32_bf16(pa, bv2, acc[ct], 0, 0, 0);
      }
    }
    if (kt + 1 < 8) writeP(buf ^ 1);
    __syncthreads();
    buf ^= 1;
  }

  const int n0 = q0 + wid * 16 + ((lane >> 4) << 2);
#pragma unroll
  for (int ct = 0; ct < 4; ++ct) {
    const int d = ct * 16 + (lane & 15);
#pragma unroll
    for (int j = 0; j < 4; ++j)
      AO[((size_t)b * Nn + n0 + j) * Ee + h * Dd + d] = f2b(acc[ct][j]);
  }
}

// ---------- K4: output projection GEMM (global_load_lds, all-bf16) -> f32 out ----------
__global__ __launch_bounds__(256, 4)
void k_outproj(const u16* __restrict__ AOp, const u16* __restrict__ Wo,
               const float* __restrict__ bo, float* __restrict__ out) {
  const int bm = blockIdx.x, bn = blockIdx.y;
  const int tid = threadIdx.x, lane = tid & 63, wid = tid >> 6;
  const int wr = wid >> 1, wc = wid & 1;

  __shared__ char smem[32768];   // A: 2x8KB at 0; B: 2x8KB at 16384

  auto stage = [&](const u16* src, int lds_base, int buf, int it) {
    const int r0 = tid >> 2, s = tid & 3;
    char* lbase = smem + lds_base + buf * 8192 + tid * 16;
#pragma unroll
    for (int R = 0; R < 2; ++R) {
      const int row = R * 64 + r0;
      const int ch = s ^ ((row >> 1) & 3);
      gload16(src + (size_t)row * Ee + it * 32 + ch * 8, lbase + R * 4096);
    }
  };

  f32x4 acc[4][4] = {};

  auto compute = [&](int buf) {
    const char* Ab = smem + buf * 8192;
    const char* Bbp = smem + 16384 + buf * 8192;
    const int q = lane >> 4;
    bf16x8 a[4], b[4];
#pragma unroll
    for (int mt = 0; mt < 4; ++mt) {
      const int row = wr * 64 + mt * 16 + (lane & 15);
      const int s = q ^ ((row >> 1) & 3);
      a[mt] = *reinterpret_cast<const bf16x8*>(Ab + row * 64 + s * 16);
    }
#pragma unroll
    for (int nt = 0; nt < 4; ++nt) {
      const int row = wc * 64 + nt * 16 + (lane & 15);
      const int s = q ^ ((row >> 1) & 3);
      b[nt] = *reinterpret_cast<const bf16x8*>(Bbp + row * 64 + s * 16);
    }
#pragma unroll
    for (int mt = 0; mt < 4; ++mt)
#pragma unroll
      for (int nt = 0; nt < 4; ++nt)
        acc[mt][nt] = __builtin_amdgcn_mfma_f32_16x16x32_bf16(a[mt], b[nt], acc[mt][nt], 0, 0, 0);
  };

  const u16* Asrc = AOp + (size_t)(bm * 128) * Ee;
  const u16* Bsrc = Wo + (size_t)(bn * 128) * Ee;
  stage(Asrc, 0, 0, 0); stage(Bsrc, 16384, 0, 0);
  __syncthreads();
  int buf = 0;
  for (int it = 0; it < 24; ++it) {
    if (it + 1 < 24) { stage(Asrc, 0, buf ^ 1, it + 1); stage(Bsrc, 16384, buf ^ 1, it + 1); }
    compute(buf);
    __syncthreads();
    buf ^= 1;
  }

#pragma unroll
  for (int mt = 0; mt < 4; ++mt) {
#pragma unroll
    for (int nt = 0; nt < 4; ++nt) {
      const int ecol = bn * 128 + wc * 64 + nt * 16 + (lane & 15);
      const int r0 = bm * 128 + wr * 64 + mt * 16 + ((lane >> 4) << 2);
      const float bs = bo[ecol];
      f32x4 v = acc[mt][nt];
#pragma unroll
      for (int j = 0; j < 4; ++j)
        out[(size_t)(r0 + j) * Ee + ecol] = v[j] + bs;
    }
  }
}

// ---------- launch ----------
extern "C" void kernel_launch(void* const* d_in, const int* in_sizes, int n_in,
                              void* d_out, int out_size, void* d_ws, size_t ws_size,
                              hipStream_t stream) {
  const float* query  = (const float*)d_in[0];
  const float* key_in = (const float*)d_in[1];
  const float* value  = (const float*)d_in[2];
  const float* sb     = (const float*)d_in[3];
  const float* eb     = (const float*)d_in[4];
  const float* Wq     = (const float*)d_in[5];
  const float* bq     = (const float*)d_in[6];
  const float* Wk     = (const float*)d_in[7];
  const float* bk     = (const float*)d_in[8];
  const float* Wv     = (const float*)d_in[9];
  const float* bv     = (const float*)d_in[10];
  const float* Wo     = (const float*)d_in[11];
  const float* bo     = (const float*)d_in[12];

  float* out0 = (float*)d_out;                        // attn_output [16,512,768]
  float* wout = out0 + (size_t)Bb * Nn * Ee;          // attn_weights [16,12,512,512]

  // workspace layout (bytes)
  char* ws = (char*)d_ws;
  const size_t off_wb = 0;                 // 4 * 768*768 bf16 = 4,718,592
  const size_t off_Q  = 4718592;           // 12,582,912 each
  const size_t off_K  = 17301504;
  const size_t off_VT = 29884416;
  const size_t off_AO = 42467328;          // end 55,050,240
  if (ws_size < 55050240) return;

  u16* wb  = (u16*)(ws + off_wb);
  u16* Qs  = (u16*)(ws + off_Q);
  u16* Kst = (u16*)(ws + off_K);
  u16* VTs = (u16*)(ws + off_VT);
  u16* AO  = (u16*)(ws + off_AO);

  k_cvtw<<<2304, 256, 0, stream>>>(Wq, Wk, Wv, Wo, wb);
  k_qkv<<<dim3(64, 6, 3), 256, 0, stream>>>(query, key_in, value, wb, bq, bk, bv, Qs, Kst, VTs);
  k_scores<<<dim3(8, Hh, Bb), 256, 0, stream>>>(Qs, Kst, sb, eb, wout);
  k_pv<<<dim3(8, Hh, Bb), 256, 0, stream>>>(wout, VTs, AO);
  k_outproj<<<dim3(64, 6), 256, 0, stream>>>(AO, wb + 3 * Ee * Ee, bo, out0);
}

// Round 4
// 267.106 us; speedup vs baseline: 1.3986x; 1.0927x over previous
//
#include <hip/hip_runtime.h>

using bf16x8 = __attribute__((ext_vector_type(8))) __bf16;
using f32x4  = __attribute__((ext_vector_type(4))) float;
using u16 = unsigned short;

constexpr int Bb = 16, Nn = 512, Ee = 768, Hh = 12, Dd = 64;

__device__ inline u16 f2b(float x) {
  union { float f; unsigned int u; } v; v.f = x;
  unsigned int r = v.u + 0x7fffu + ((v.u >> 16) & 1u);
  return (u16)(r >> 16);
}

__device__ inline unsigned cvtpk(float lo, float hi) {
  unsigned r;
  asm("v_cvt_pk_bf16_f32 %0, %1, %2" : "=v"(r) : "v"(lo), "v"(hi));
  return r;
}

__device__ inline void gload16(const void* g, void* l) {
  __builtin_amdgcn_global_load_lds((const __attribute__((address_space(1))) void*)g,
                                   (__attribute__((address_space(3))) void*)l, 16, 0, 0);
}

// ---------- K0: convert the 4 weight matrices f32 -> bf16 ----------
__global__ void k_cvtw(const float* __restrict__ w0, const float* __restrict__ w1,
                       const float* __restrict__ w2, const float* __restrict__ w3,
                       u16* __restrict__ dst) {
  int idx = blockIdx.x * 256 + threadIdx.x;     // one float4 per thread
  constexpr int per = Ee * Ee / 4;              // 147456
  int m = idx / per, r = idx - m * per;
  const float* src = (m == 0) ? w0 : (m == 1) ? w1 : (m == 2) ? w2 : w3;
  float4 v = reinterpret_cast<const float4*>(src)[r];
  ushort4 o = make_ushort4(f2b(v.x), f2b(v.y), f2b(v.z), f2b(v.w));
  reinterpret_cast<ushort4*>(dst)[idx] = o;
}

// ---------- K1: QKV projection GEMM, global_load_lds staging ----------
__global__ __launch_bounds__(256, 3)
void k_qkv(const float* __restrict__ xq, const float* __restrict__ xk, const float* __restrict__ xv,
           const u16* __restrict__ wb, const float* __restrict__ bq, const float* __restrict__ bk,
           const float* __restrict__ bv, u16* __restrict__ Q, u16* __restrict__ K,
           u16* __restrict__ VT) {
  const int mat = blockIdx.z;
  const float* X = (mat == 0) ? xq : (mat == 1) ? xk : xv;
  const u16* W = wb + (size_t)mat * Ee * Ee;
  const float* bias = (mat == 0) ? bq : (mat == 1) ? bk : bv;
  const int bm = blockIdx.x, bn = blockIdx.y;
  const int tid = threadIdx.x, lane = tid & 63, wid = tid >> 6;
  const int wr = wid >> 1, wc = wid & 1;

  __shared__ char smem[49152];   // A: 2x16KB at 0; B: 2x8KB at 32768

  auto stageA = [&](int buf, int it) {
    const int r0 = tid >> 3, s = tid & 7;
    char* lbase = smem + buf * 16384 + tid * 16;
#pragma unroll
    for (int R = 0; R < 4; ++R) {
      const int row = R * 32 + r0;
      const int ch = s ^ (row & 7);
      gload16(X + (size_t)(bm * 128 + row) * Ee + it * 32 + ch * 4, lbase + R * 4096);
    }
  };
  auto stageB = [&](int buf, int it) {
    const int r0 = tid >> 2, s = tid & 3;
    char* lbase = smem + 32768 + buf * 8192 + tid * 16;
#pragma unroll
    for (int R = 0; R < 2; ++R) {
      const int row = R * 64 + r0;
      const int ch = s ^ ((row >> 1) & 3);
      gload16(W + (size_t)(bn * 128 + row) * Ee + it * 32 + ch * 8, lbase + R * 4096);
    }
  };

  f32x4 acc[4][4] = {};

  auto compute = [&](int buf) {
    const char* Ab = smem + buf * 16384;
    const char* Bbp = smem + 32768 + buf * 8192;
    const int q = lane >> 4;
    bf16x8 a[4], b[4];
#pragma unroll
    for (int mt = 0; mt < 4; ++mt) {
      const int row = wr * 64 + mt * 16 + (lane & 15);
      const int s0 = (2 * q) ^ (row & 7), s1 = (2 * q + 1) ^ (row & 7);
      f32x4 f0 = *reinterpret_cast<const f32x4*>(Ab + row * 128 + s0 * 16);
      f32x4 f1 = *reinterpret_cast<const f32x4*>(Ab + row * 128 + s1 * 16);
      union { unsigned u[4]; bf16x8 v; } cv;
      cv.u[0] = cvtpk(f0[0], f0[1]);
      cv.u[1] = cvtpk(f0[2], f0[3]);
      cv.u[2] = cvtpk(f1[0], f1[1]);
      cv.u[3] = cvtpk(f1[2], f1[3]);
      a[mt] = cv.v;
    }
#pragma unroll
    for (int nt = 0; nt < 4; ++nt) {
      const int row = wc * 64 + nt * 16 + (lane & 15);
      const int s = q ^ ((row >> 1) & 3);
      b[nt] = *reinterpret_cast<const bf16x8*>(Bbp + row * 64 + s * 16);
    }
#pragma unroll
    for (int mt = 0; mt < 4; ++mt)
#pragma unroll
      for (int nt = 0; nt < 4; ++nt)
        acc[mt][nt] = __builtin_amdgcn_mfma_f32_16x16x32_bf16(a[mt], b[nt], acc[mt][nt], 0, 0, 0);
  };

  stageA(0, 0); stageB(0, 0);
  __syncthreads();
  int buf = 0;
  for (int it = 0; it < 24; ++it) {
    if (it + 1 < 24) { stageA(buf ^ 1, it + 1); stageB(buf ^ 1, it + 1); }
    compute(buf);
    __syncthreads();
    buf ^= 1;
  }

  // epilogue via LDS transpose tile [128][136] u16 for coalesced 128B stores
  u16* sm16 = (u16*)smem;
  if (mat < 2) {
    u16* dst = (mat == 0) ? Q : K;
    const float sc = (mat == 0) ? 0.125f : 1.0f;
#pragma unroll
    for (int mt = 0; mt < 4; ++mt) {
      const int n_l0 = wr * 64 + mt * 16 + ((lane >> 4) << 2);
#pragma unroll
      for (int nt = 0; nt < 4; ++nt) {
        const int e_l = wc * 64 + nt * 16 + (lane & 15);
        const float bs = bias[bn * 128 + e_l];
#pragma unroll
        for (int j = 0; j < 4; ++j)
          sm16[(n_l0 + j) * 136 + e_l] = f2b((acc[mt][nt][j] + bs) * sc);
      }
    }
    __syncthreads();
    const int row = tid >> 1, half = tid & 1;
    const int n = bm * 128 + row, b = n >> 9, n0 = n & 511, h = bn * 2 + half;
    u16* gp = dst + ((size_t)(b * Hh + h) * Nn + n0) * Dd;
    const u16* sp = sm16 + row * 136 + half * 64;
#pragma unroll
    for (int i = 0; i < 8; ++i)
      *reinterpret_cast<int4*>(gp + i * 8) = *reinterpret_cast<const int4*>(sp + i * 8);
  } else {
#pragma unroll
    for (int mt = 0; mt < 4; ++mt) {
      const int n_l0 = wr * 64 + mt * 16 + ((lane >> 4) << 2);
#pragma unroll
      for (int nt = 0; nt < 4; ++nt) {
        const int e_l = wc * 64 + nt * 16 + (lane & 15);
        const float bs = bias[bn * 128 + e_l];
#pragma unroll
        for (int j = 0; j < 4; ++j)
          sm16[e_l * 136 + n_l0 + j] = f2b(acc[mt][nt][j] + bs);
      }
    }
    __syncthreads();
    const int er = tid >> 1, half = tid & 1;
    const int b = bm >> 2, h = bn * 2 + (er >> 6), d = er & 63;
    u16* gp = VT + ((size_t)(b * Hh + h) * Dd + d) * Nn + (bm & 3) * 128 + half * 64;
    const u16* sp = sm16 + er * 136 + half * 64;
#pragma unroll
    for (int i = 0; i < 8; ++i)
      *reinterpret_cast<int4*>(gp + i * 8) = *reinterpret_cast<const int4*>(sp + i * 8);
  }
}

// ---------- K2: scores = QK^T + (spatial+edge), softmax, write f32 weights ----------
// SWAPPED operands: mfma(K_frag, Q_frag) -> lane holds S[q=lane&15-of-wave-tile][keys
// t*16 + (lane>>4)*4 + j]. Row spread over only 4 lanes; bias/store are float4.
__global__ __launch_bounds__(256, 2)
void k_scores(const u16* __restrict__ Q, const u16* __restrict__ K,
              const float* __restrict__ sb, const float* __restrict__ eb,
              float* __restrict__ wout) {
  const int qb = blockIdx.x, h = blockIdx.y, b = blockIdx.z;
  const int bh = b * Hh + h;
  const int q0 = qb * 64;
  const int tid = threadIdx.x, lane = tid & 63, wid = tid >> 6;

  __shared__ u16 Ksm[2][64 * 64];   // [key][d] bf16, XOR-swizzled 16B chunks

  bf16x8 aq[2];
  {
    const u16* qp = Q + ((size_t)bh * Nn + q0 + wid * 16 + (lane & 15)) * Dd + (lane >> 4) * 8;
    aq[0] = *reinterpret_cast<const bf16x8*>(qp);
    aq[1] = *reinterpret_cast<const bf16x8*>(qp + 32);
  }

  f32x4 acc[32] = {};
  int4 kreg[2];

  auto loadK = [&](int kt) {
#pragma unroll
    for (int i = 0; i < 2; ++i) {
      const int s = i * 256 + tid, row = s >> 3, c8 = s & 7;
      kreg[i] = *reinterpret_cast<const int4*>(
          K + ((size_t)bh * Nn + kt * 64 + row) * Dd + c8 * 8);
    }
  };
  auto writeK = [&](int buf) {
#pragma unroll
    for (int i = 0; i < 2; ++i) {
      const int s = i * 256 + tid, row = s >> 3, c8 = s & 7;
      *reinterpret_cast<int4*>(reinterpret_cast<char*>(Ksm[buf]) + row * 128 +
                               ((c8 ^ (row & 7)) * 16)) = kreg[i];
    }
  };

  loadK(0); writeK(0);
  __syncthreads();
  int buf = 0;
#pragma unroll
  for (int kt = 0; kt < 8; ++kt) {
    if (kt + 1 < 8) loadK(kt + 1);
#pragma unroll
    for (int kk = 0; kk < 2; ++kk) {
#pragma unroll
      for (int ct = 0; ct < 4; ++ct) {
        const int kr = ct * 16 + (lane & 15);
        const int chunk = (lane >> 4) + kk * 4;
        bf16x8 bk = *reinterpret_cast<const bf16x8*>(
            reinterpret_cast<const char*>(Ksm[buf]) + kr * 128 + ((chunk ^ (kr & 7)) * 16));
        // swapped: A = K rows (key), B = Q rows (q)
        acc[kt * 4 + ct] = __builtin_amdgcn_mfma_f32_16x16x32_bf16(bk, aq[kk], acc[kt * 4 + ct], 0, 0, 0);
      }
    }
    if (kt + 1 < 8) writeK(buf ^ 1);
    __syncthreads();
    buf ^= 1;
  }

  // epilogue: lane's q-row = q0 + wid*16 + (lane&15); keys t*16 + (lane>>4)*4 + j
  const int q4 = lane >> 4;
  const int rq = q0 + wid * 16 + (lane & 15);
  const float4* sb4 = reinterpret_cast<const float4*>(sb + ((size_t)b * Nn + rq) * Nn);
  const float4* eb4 = reinterpret_cast<const float4*>(eb + ((size_t)b * Nn + rq) * Nn);
#pragma unroll
  for (int t = 0; t < 32; ++t) {
    float4 s4 = sb4[t * 4 + q4];
    float4 e4 = eb4[t * 4 + q4];
    acc[t][0] += s4.x + e4.x;
    acc[t][1] += s4.y + e4.y;
    acc[t][2] += s4.z + e4.z;
    acc[t][3] += s4.w + e4.w;
  }

  float mx = -1e30f;
#pragma unroll
  for (int t = 0; t < 32; ++t)
#pragma unroll
    for (int j = 0; j < 4; ++j) mx = fmaxf(mx, acc[t][j]);
  mx = fmaxf(mx, __shfl_xor(mx, 16));
  mx = fmaxf(mx, __shfl_xor(mx, 32));

  float sum = 0.f;
#pragma unroll
  for (int t = 0; t < 32; ++t)
#pragma unroll
    for (int j = 0; j < 4; ++j) {
      float p = exp2f((acc[t][j] - mx) * 1.44269504f);
      acc[t][j] = p;
      sum += p;
    }
  sum += __shfl_xor(sum, 16);
  sum += __shfl_xor(sum, 32);
  const float inv = 1.0f / sum;

  float4* wp4 = reinterpret_cast<float4*>(wout + ((size_t)bh * Nn + rq) * Nn);
#pragma unroll
  for (int t = 0; t < 32; ++t) {
    float4 o;
    o.x = acc[t][0] * inv; o.y = acc[t][1] * inv;
    o.z = acc[t][2] * inv; o.w = acc[t][3] * inv;
    wp4[t * 4 + q4] = o;
  }
}

// ---------- K3: PV GEMM: O = W[512x512] @ V[512x64] ----------
__global__ __launch_bounds__(256, 2)
void k_pv(const float* __restrict__ wts, const u16* __restrict__ VT, u16* __restrict__ AO) {
  const int qb = blockIdx.x, h = blockIdx.y, b = blockIdx.z;
  const int bh = b * Hh + h;
  const int q0 = qb * 64;
  const int tid = threadIdx.x, lane = tid & 63, wid = tid >> 6;

  __shared__ u16 Ps[2][64 * 64];   // [q][key] bf16, XOR-swizzled

  f32x4 acc[4] = {};
  float4 pr[4];

  auto loadP = [&](int kt) {
    const int row = tid >> 4, c4 = (tid & 15) * 4;
    const float* p = wts + ((size_t)bh * Nn + q0 + row) * Nn + kt * 64 + c4;
#pragma unroll
    for (int i = 0; i < 4; ++i)
      pr[i] = *reinterpret_cast<const float4*>(p + (size_t)(i * 16) * Nn);
  };
  auto writeP = [&](int buf) {
    const int row0 = tid >> 4, c4 = (tid & 15) * 4;
#pragma unroll
    for (int i = 0; i < 4; ++i) {
      const int row = row0 + i * 16;
      float4 v = pr[i];
      ushort4 u = make_ushort4(f2b(v.x), f2b(v.y), f2b(v.z), f2b(v.w));
      *reinterpret_cast<ushort4*>(reinterpret_cast<char*>(Ps[buf]) + row * 128 +
                                  ((c4 * 2) ^ ((row & 7) << 4))) = u;
    }
  };

  loadP(0); writeP(0);
  __syncthreads();
  int buf = 0;
  for (int kt = 0; kt < 8; ++kt) {
    if (kt + 1 < 8) loadP(kt + 1);
#pragma unroll
    for (int kk = 0; kk < 2; ++kk) {
      const int qr = wid * 16 + (lane & 15);
      const int chunk = (lane >> 4) + kk * 4;
      bf16x8 pa = *reinterpret_cast<const bf16x8*>(
          reinterpret_cast<const char*>(Ps[buf]) + qr * 128 + ((chunk ^ (qr & 7)) * 16));
#pragma unroll
      for (int ct = 0; ct < 4; ++ct) {
        const u16* vp = VT + ((size_t)bh * Dd + ct * 16 + (lane & 15)) * Nn +
                        kt * 64 + kk * 32 + (lane >> 4) * 8;
        bf16x8 bv2 = *reinterpret_cast<const bf16x8*>(vp);
        acc[ct] = __builtin_amdgcn_mfma_f32_16x16x32_bf16(pa, bv2, acc[ct], 0, 0, 0);
      }
    }
    if (kt + 1 < 8) writeP(buf ^ 1);
    __syncthreads();
    buf ^= 1;
  }

  const int n0 = q0 + wid * 16 + ((lane >> 4) << 2);
#pragma unroll
  for (int ct = 0; ct < 4; ++ct) {
    const int d = ct * 16 + (lane & 15);
#pragma unroll
    for (int j = 0; j < 4; ++j)
      AO[((size_t)b * Nn + n0 + j) * Ee + h * Dd + d] = f2b(acc[ct][j]);
  }
}

// ---------- K4: output projection GEMM (global_load_lds, all-bf16) -> f32 out ----------
__global__ __launch_bounds__(256, 4)
void k_outproj(const u16* __restrict__ AOp, const u16* __restrict__ Wo,
               const float* __restrict__ bo, float* __restrict__ out) {
  const int bm = blockIdx.x, bn = blockIdx.y;
  const int tid = threadIdx.x, lane = tid & 63, wid = tid >> 6;
  const int wr = wid >> 1, wc = wid & 1;

  __shared__ char smem[32768];   // A: 2x8KB at 0; B: 2x8KB at 16384

  auto stage = [&](const u16* src, int lds_base, int buf, int it) {
    const int r0 = tid >> 2, s = tid & 3;
    char* lbase = smem + lds_base + buf * 8192 + tid * 16;
#pragma unroll
    for (int R = 0; R < 2; ++R) {
      const int row = R * 64 + r0;
      const int ch = s ^ ((row >> 1) & 3);
      gload16(src + (size_t)row * Ee + it * 32 + ch * 8, lbase + R * 4096);
    }
  };

  f32x4 acc[4][4] = {};

  auto compute = [&](int buf) {
    const char* Ab = smem + buf * 8192;
    const char* Bbp = smem + 16384 + buf * 8192;
    const int q = lane >> 4;
    bf16x8 a[4], b[4];
#pragma unroll
    for (int mt = 0; mt < 4; ++mt) {
      const int row = wr * 64 + mt * 16 + (lane & 15);
      const int s = q ^ ((row >> 1) & 3);
      a[mt] = *reinterpret_cast<const bf16x8*>(Ab + row * 64 + s * 16);
    }
#pragma unroll
    for (int nt = 0; nt < 4; ++nt) {
      const int row = wc * 64 + nt * 16 + (lane & 15);
      const int s = q ^ ((row >> 1) & 3);
      b[nt] = *reinterpret_cast<const bf16x8*>(Bbp + row * 64 + s * 16);
    }
#pragma unroll
    for (int mt = 0; mt < 4; ++mt)
#pragma unroll
      for (int nt = 0; nt < 4; ++nt)
        acc[mt][nt] = __builtin_amdgcn_mfma_f32_16x16x32_bf16(a[mt], b[nt], acc[mt][nt], 0, 0, 0);
  };

  const u16* Asrc = AOp + (size_t)(bm * 128) * Ee;
  const u16* Bsrc = Wo + (size_t)(bn * 128) * Ee;
  stage(Asrc, 0, 0, 0); stage(Bsrc, 16384, 0, 0);
  __syncthreads();
  int buf = 0;
  for (int it = 0; it < 24; ++it) {
    if (it + 1 < 24) { stage(Asrc, 0, buf ^ 1, it + 1); stage(Bsrc, 16384, buf ^ 1, it + 1); }
    compute(buf);
    __syncthreads();
    buf ^= 1;
  }

#pragma unroll
  for (int mt = 0; mt < 4; ++mt) {
#pragma unroll
    for (int nt = 0; nt < 4; ++nt) {
      const int ecol = bn * 128 + wc * 64 + nt * 16 + (lane & 15);
      const int r0 = bm * 128 + wr * 64 + mt * 16 + ((lane >> 4) << 2);
      const float bs = bo[ecol];
      f32x4 v = acc[mt][nt];
#pragma unroll
      for (int j = 0; j < 4; ++j)
        out[(size_t)(r0 + j) * Ee + ecol] = v[j] + bs;
    }
  }
}

// ---------- launch ----------
extern "C" void kernel_launch(void* const* d_in, const int* in_sizes, int n_in,
                              void* d_out, int out_size, void* d_ws, size_t ws_size,
                              hipStream_t stream) {
  const float* query  = (const float*)d_in[0];
  const float* key_in = (const float*)d_in[1];
  const float* value  = (const float*)d_in[2];
  const float* sb     = (const float*)d_in[3];
  const float* eb     = (const float*)d_in[4];
  const float* Wq     = (const float*)d_in[5];
  const float* bq     = (const float*)d_in[6];
  const float* Wk     = (const float*)d_in[7];
  const float* bk     = (const float*)d_in[8];
  const float* Wv     = (const float*)d_in[9];
  const float* bv     = (const float*)d_in[10];
  const float* Wo     = (const float*)d_in[11];
  const float* bo     = (const float*)d_in[12];

  float* out0 = (float*)d_out;                        // attn_output [16,512,768]
  float* wout = out0 + (size_t)Bb * Nn * Ee;          // attn_weights [16,12,512,512]

  // workspace layout (bytes)
  char* ws = (char*)d_ws;
  const size_t off_wb = 0;                 // 4 * 768*768 bf16 = 4,718,592
  const size_t off_Q  = 4718592;           // 12,582,912 each
  const size_t off_K  = 17301504;
  const size_t off_VT = 29884416;
  const size_t off_AO = 42467328;          // end 55,050,240
  if (ws_size < 55050240) return;

  u16* wb  = (u16*)(ws + off_wb);
  u16* Qs  = (u16*)(ws + off_Q);
  u16* Kst = (u16*)(ws + off_K);
  u16* VTs = (u16*)(ws + off_VT);
  u16* AO  = (u16*)(ws + off_AO);

  k_cvtw<<<2304, 256, 0, stream>>>(Wq, Wk, Wv, Wo, wb);
  k_qkv<<<dim3(64, 6, 3), 256, 0, stream>>>(query, key_in, value, wb, bq, bk, bv, Qs, Kst, VTs);
  k_scores<<<dim3(8, Hh, Bb), 256, 0, stream>>>(Qs, Kst, sb, eb, wout);
  k_pv<<<dim3(8, Hh, Bb), 256, 0, stream>>>(wout, VTs, AO);
  k_outproj<<<dim3(64, 6), 256, 0, stream>>>(AO, wb + 3 * Ee * Ee, bo, out0);
}